// Round 1
// baseline (455.743 us; speedup 1.0000x reference)
//
#include <hip/hip_runtime.h>
#include <hip/hip_bf16.h>

#define DIMSZ 1024
#define NBATCH 4
#define SEQLEN 4096
#define NHEAD 16
#define DHEAD 64
#define MROWS 16384      // NBATCH*SEQLEN
#define NQKV 3072
#define NX 16777216L     // x elements
#define NW 1048576L      // weight elements each

typedef __attribute__((ext_vector_type(8))) short bf16x8;
typedef __attribute__((ext_vector_type(4))) float f32x4;

__device__ __forceinline__ unsigned short f2bf(float f) {
    union { float f; unsigned int i; } c; c.f = f;
    unsigned int x = c.i;
    // round-to-nearest-even
    unsigned int r = (x + 0x7fffu + ((x >> 16) & 1u)) >> 16;
    return (unsigned short)r;
}

__device__ __forceinline__ void unp4(const unsigned short* p, float* f) {
    uint2 w = *(const uint2*)p;
    union { unsigned int i; float f; } c;
    c.i = w.x << 16;           f[0] = c.f;
    c.i = w.x & 0xffff0000u;   f[1] = c.f;
    c.i = w.y << 16;           f[2] = c.f;
    c.i = w.y & 0xffff0000u;   f[3] = c.f;
}

__device__ __forceinline__ void async16(const void* g, void* l) {
    __builtin_amdgcn_global_load_lds(
        (const __attribute__((address_space(1))) void*)g,
        (__attribute__((address_space(3))) void*)l,
        16, 0, 0);
}

// ---------------- kernel 1: casts + weight packing + stdp passthrough ------
__global__ __launch_bounds__(256) void cast_pack(
    const float* __restrict__ x, const float* __restrict__ Wq,
    const float* __restrict__ Wk, const float* __restrict__ Wv,
    const float* __restrict__ Wo, const float* __restrict__ stdp,
    unsigned short* __restrict__ xb, unsigned short* __restrict__ Wqkv,
    unsigned short* __restrict__ Wob, float* __restrict__ outTail)
{
    long i4 = ((long)blockIdx.x * 256 + threadIdx.x) * 4;
    const float* src; unsigned short* dst; long off;
    if (i4 < NX)               { src = x;  dst = xb;          off = i4; }
    else if (i4 < NX + NW)     { src = Wq; dst = Wqkv;        off = i4 - NX; }
    else if (i4 < NX + 2*NW)   { src = Wk; dst = Wqkv + NW;   off = i4 - NX - NW; }
    else if (i4 < NX + 3*NW)   { src = Wv; dst = Wqkv + 2*NW; off = i4 - NX - 2*NW; }
    else                       { src = Wo; dst = Wob;         off = i4 - NX - 3*NW; }
    float4 v = *(const float4*)(src + off);
    union { unsigned short u[4]; uint2 p; } o;
    o.u[0] = f2bf(v.x); o.u[1] = f2bf(v.y); o.u[2] = f2bf(v.z); o.u[3] = f2bf(v.w);
    *(uint2*)(dst + off) = o.p;
    if (blockIdx.x == 0 && threadIdx.x < NHEAD) outTail[threadIdx.x] = stdp[threadIdx.x];
}

// ---------------- kernel 2: fused QKV GEMM (bf16 MFMA, m97 structure) ------
// C[m][f] = sum_k xb[m][k]*Wqkv[f][k];  f<1024 -> Q, <2048 -> K, else V
// epilogue: +bias, elu+1 on Q/K, write bf16 [m][1024] per tensor ((b,n,h,dh))
__global__ __launch_bounds__(256) void qkv_gemm(
    const unsigned short* __restrict__ A, const unsigned short* __restrict__ W,
    const float* __restrict__ bq, const float* __restrict__ bk,
    const float* __restrict__ bv,
    unsigned short* __restrict__ Qb, unsigned short* __restrict__ Kb,
    unsigned short* __restrict__ Vb)
{
    __shared__ unsigned short As[128 * 32];
    __shared__ unsigned short Bs[128 * 32];
    const int K = DIMSZ;
    int t = threadIdx.x;
    int wave = t >> 6, lane = t & 63;
    int lr = lane & 15, lk = (lane >> 4) * 8;
    int m0 = blockIdx.x * 128;
    int c0 = blockIdx.y * 128;
    int rw = (wave >> 1) * 64, cw = (wave & 1) * 64;

    const unsigned short* Ap = A + (long)(m0 + (t >> 2)) * K + (t & 3) * 8;
    const unsigned short* Wp = W + (long)(c0 + (t >> 2)) * K + (t & 3) * 8;
    char* AsW = (char*)As + wave * 1024;
    char* BsW = (char*)Bs + wave * 1024;

    f32x4 acc[4][4];
    #pragma unroll
    for (int i = 0; i < 4; ++i)
        #pragma unroll
        for (int j = 0; j < 4; ++j) acc[i][j] = (f32x4){0.f, 0.f, 0.f, 0.f};

    for (int k0 = 0; k0 < K; k0 += 32) {
        async16(Ap + k0,          AsW);
        async16(Ap + 64 * K + k0, AsW + 4096);
        async16(Wp + k0,          BsW);
        async16(Wp + 64 * K + k0, BsW + 4096);
        __syncthreads();
        bf16x8 af[4], bfr[4];
        #pragma unroll
        for (int i = 0; i < 4; ++i)
            af[i] = *(const bf16x8*)(As + (rw + 16 * i + lr) * 32 + lk);
        #pragma unroll
        for (int j = 0; j < 4; ++j)
            bfr[j] = *(const bf16x8*)(Bs + (cw + 16 * j + lr) * 32 + lk);
        #pragma unroll
        for (int i = 0; i < 4; ++i)
            #pragma unroll
            for (int j = 0; j < 4; ++j)
                acc[i][j] = __builtin_amdgcn_mfma_f32_16x16x32_bf16(af[i], bfr[j], acc[i][j], 0, 0, 0);
        __syncthreads();
    }

    int q4 = (lane >> 4) * 4;
    #pragma unroll
    for (int j = 0; j < 4; ++j) {
        int f = c0 + cw + 16 * j + lr;
        int proj = f >> 10, c = f & 1023;
        float bias = proj == 0 ? bq[c] : (proj == 1 ? bk[c] : bv[c]);
        unsigned short* dst = proj == 0 ? Qb : (proj == 1 ? Kb : Vb);
        bool qk = proj < 2;
        #pragma unroll
        for (int i = 0; i < 4; ++i) {
            #pragma unroll
            for (int r = 0; r < 4; ++r) {
                int gm = m0 + rw + 16 * i + q4 + r;
                float p = acc[i][j][r] + bias;
                if (qk) p = p > 0.f ? p + 1.f : __expf(p);  // elu(p)+1
                dst[(long)gm * DIMSZ + c] = f2bf(p);
            }
        }
    }
}

// ---------------- kernel 3: KV^T and Ksum reduction (VALU outer product) ---
// KVt[bh][v][d] = sum_n K[b,n,h,d]*V[b,n,h,v];  Ksum[bh][d] = sum_n K
__global__ __launch_bounds__(256) void kv_reduce(
    const unsigned short* __restrict__ Kb, const unsigned short* __restrict__ Vb,
    float* __restrict__ KVt, float* __restrict__ Ksum)
{
    int bh = blockIdx.x, split = blockIdx.y;
    int b = bh >> 4, h = bh & 15;
    int t = threadIdx.x;
    int d0 = (t & 15) * 4, v0 = (t >> 4) * 4;
    long base = ((long)(b * SEQLEN + split * 256)) * DIMSZ + h * DHEAD;
    float acc[4][4] = {{0.f}};
    float ks[4] = {0.f, 0.f, 0.f, 0.f};
    for (int n = 0; n < 256; ++n) {
        long rb = base + (long)n * DIMSZ;
        float kf[4], vf[4];
        unp4(Kb + rb + d0, kf);
        unp4(Vb + rb + v0, vf);
        if (v0 == 0) { ks[0] += kf[0]; ks[1] += kf[1]; ks[2] += kf[2]; ks[3] += kf[3]; }
        #pragma unroll
        for (int a = 0; a < 4; ++a)
            #pragma unroll
            for (int c = 0; c < 4; ++c) acc[a][c] += kf[a] * vf[c];
    }
    float* kvb = KVt + bh * 4096;
    #pragma unroll
    for (int c = 0; c < 4; ++c)
        #pragma unroll
        for (int a = 0; a < 4; ++a)
            atomicAdd(kvb + (v0 + c) * 64 + d0 + a, acc[a][c]);
    if (v0 == 0) {
        #pragma unroll
        for (int a = 0; a < 4; ++a) atomicAdd(Ksum + bh * 64 + d0 + a, ks[a]);
    }
}

// ---------------- kernel 4: denom + numerator MFMA + scale -> attn bf16 ----
__global__ __launch_bounds__(256) void attn_kernel(
    const unsigned short* __restrict__ Qb, const float* __restrict__ KVt,
    const float* __restrict__ Ksum, const float* __restrict__ stdp,
    unsigned short* __restrict__ attn)
{
    __shared__ unsigned short Bsh[64 * 64];   // KVt as bf16, [v][d]
    __shared__ float ksum_s[64];
    __shared__ float dinv[256];
    int t = threadIdx.x;
    int rc = blockIdx.x;   // 16 row-chunks of 256
    int bh = blockIdx.y;   // 64
    int b = bh >> 4, h = bh & 15;

    const float* kvsrc = KVt + bh * 4096;
    #pragma unroll
    for (int u = 0; u < 16; u += 4) {
        float4 v = *(const float4*)(kvsrc + t * 16 + u);
        union { unsigned short us[4]; uint2 p; } o;
        o.us[0] = f2bf(v.x); o.us[1] = f2bf(v.y); o.us[2] = f2bf(v.z); o.us[3] = f2bf(v.w);
        *(uint2*)(Bsh + t * 16 + u) = o.p;
    }
    if (t < 64) ksum_s[t] = Ksum[bh * 64 + t];
    __syncthreads();

    // denominator for row n = rc*256 + t
    int n = rc * 256 + t;
    const unsigned short* qrow = Qb + ((long)(b * SEQLEN + n)) * DIMSZ + h * DHEAD;
    float s = 0.f;
    #pragma unroll
    for (int u = 0; u < 64; u += 4) {
        float qf[4]; unp4(qrow + u, qf);
        s += qf[0] * ksum_s[u] + qf[1] * ksum_s[u + 1] + qf[2] * ksum_s[u + 2] + qf[3] * ksum_s[u + 3];
    }
    float sg = 1.f / (1.f + __expf(-stdp[h]));
    dinv[t] = sg / (s + 1e-6f);
    __syncthreads();

    // numerator: Q(256x64) @ KVt^T(64x64), per-wave 64 rows
    int wave = t >> 6, lane = t & 63, lr = lane & 15, lk = (lane >> 4) * 8;
    int rowbase = rc * 256 + wave * 64;
    f32x4 acc[4][4];
    #pragma unroll
    for (int i = 0; i < 4; ++i)
        #pragma unroll
        for (int j = 0; j < 4; ++j) acc[i][j] = (f32x4){0.f, 0.f, 0.f, 0.f};

    #pragma unroll
    for (int s0 = 0; s0 < 64; s0 += 32) {
        bf16x8 af[4], bfr[4];
        #pragma unroll
        for (int i = 0; i < 4; ++i)
            af[i] = *(const bf16x8*)(Qb + ((long)(b * SEQLEN + rowbase + 16 * i + lr)) * DIMSZ + h * DHEAD + lk + s0);
        #pragma unroll
        for (int j = 0; j < 4; ++j)
            bfr[j] = *(const bf16x8*)(Bsh + (16 * j + lr) * 64 + lk + s0);
        #pragma unroll
        for (int i = 0; i < 4; ++i)
            #pragma unroll
            for (int j = 0; j < 4; ++j)
                acc[i][j] = __builtin_amdgcn_mfma_f32_16x16x32_bf16(af[i], bfr[j], acc[i][j], 0, 0, 0);
    }

    int q4 = (lane >> 4) * 4;
    #pragma unroll
    for (int j = 0; j < 4; ++j) {
        int v = 16 * j + lr;
        #pragma unroll
        for (int i = 0; i < 4; ++i) {
            #pragma unroll
            for (int r = 0; r < 4; ++r) {
                int rowin = wave * 64 + 16 * i + q4 + r;
                int nn = rc * 256 + rowin;
                float val = acc[i][j][r] * dinv[rowin];
                attn[((long)(b * SEQLEN + nn)) * DIMSZ + h * DHEAD + v] = f2bf(val);
            }
        }
    }
}

// ---------------- kernel 5: output GEMM (attn @ Wo^T + bo), f32 out --------
__global__ __launch_bounds__(256) void out_gemm(
    const unsigned short* __restrict__ A, const unsigned short* __restrict__ W,
    const float* __restrict__ bo, float* __restrict__ out)
{
    __shared__ unsigned short As[128 * 32];
    __shared__ unsigned short Bs[128 * 32];
    const int K = DIMSZ;
    int t = threadIdx.x;
    int wave = t >> 6, lane = t & 63;
    int lr = lane & 15, lk = (lane >> 4) * 8;
    int m0 = blockIdx.x * 128;
    int c0 = blockIdx.y * 128;
    int rw = (wave >> 1) * 64, cw = (wave & 1) * 64;

    const unsigned short* Ap = A + (long)(m0 + (t >> 2)) * K + (t & 3) * 8;
    const unsigned short* Wp = W + (long)(c0 + (t >> 2)) * K + (t & 3) * 8;
    char* AsW = (char*)As + wave * 1024;
    char* BsW = (char*)Bs + wave * 1024;

    f32x4 acc[4][4];
    #pragma unroll
    for (int i = 0; i < 4; ++i)
        #pragma unroll
        for (int j = 0; j < 4; ++j) acc[i][j] = (f32x4){0.f, 0.f, 0.f, 0.f};

    for (int k0 = 0; k0 < K; k0 += 32) {
        async16(Ap + k0,          AsW);
        async16(Ap + 64 * K + k0, AsW + 4096);
        async16(Wp + k0,          BsW);
        async16(Wp + 64 * K + k0, BsW + 4096);
        __syncthreads();
        bf16x8 af[4], bfr[4];
        #pragma unroll
        for (int i = 0; i < 4; ++i)
            af[i] = *(const bf16x8*)(As + (rw + 16 * i + lr) * 32 + lk);
        #pragma unroll
        for (int j = 0; j < 4; ++j)
            bfr[j] = *(const bf16x8*)(Bs + (cw + 16 * j + lr) * 32 + lk);
        #pragma unroll
        for (int i = 0; i < 4; ++i)
            #pragma unroll
            for (int j = 0; j < 4; ++j)
                acc[i][j] = __builtin_amdgcn_mfma_f32_16x16x32_bf16(af[i], bfr[j], acc[i][j], 0, 0, 0);
        __syncthreads();
    }

    int q4 = (lane >> 4) * 4;
    #pragma unroll
    for (int j = 0; j < 4; ++j) {
        int f = c0 + cw + 16 * j + lr;
        float bias = bo[f];
        #pragma unroll
        for (int i = 0; i < 4; ++i) {
            #pragma unroll
            for (int r = 0; r < 4; ++r) {
                int gm = m0 + rw + 16 * i + q4 + r;
                out[(long)gm * DIMSZ + f] = acc[i][j][r] + bias;
            }
        }
    }
}

extern "C" void kernel_launch(void* const* d_in, const int* in_sizes, int n_in,
                              void* d_out, int out_size, void* d_ws, size_t ws_size,
                              hipStream_t stream) {
    const float* x    = (const float*)d_in[0];
    const float* Wq   = (const float*)d_in[1];
    const float* bq   = (const float*)d_in[2];
    const float* Wk   = (const float*)d_in[3];
    const float* bk   = (const float*)d_in[4];
    const float* Wv   = (const float*)d_in[5];
    const float* bv   = (const float*)d_in[6];
    const float* Wo   = (const float*)d_in[7];
    const float* bo   = (const float*)d_in[8];
    const float* stdp = (const float*)d_in[9];
    float* out = (float*)d_out;

    char* ws = (char*)d_ws;
    // workspace layout (bytes); attn reuses xb (dead after qkv_gemm)
    unsigned short* xb   = (unsigned short*)(ws);                 //  32 MB
    unsigned short* Wqkv = (unsigned short*)(ws + 33554432L);     //   6 MB
    unsigned short* Wob  = (unsigned short*)(ws + 39845888L);     //   2 MB
    unsigned short* Qb   = (unsigned short*)(ws + 41943040L);     //  32 MB
    unsigned short* Kb   = (unsigned short*)(ws + 75497472L);     //  32 MB
    unsigned short* Vb   = (unsigned short*)(ws + 109051904L);    //  32 MB
    float* KVt           = (float*)(ws + 142606336L);             //   1 MB
    float* Ksum          = (float*)(ws + 143654912L);             //  16 KB
    unsigned short* attn = xb;

    // zero the atomic accumulators (KVt + Ksum are contiguous)
    hipMemsetAsync(KVt, 0, 64L * 4096 * 4 + 64L * 64 * 4, stream);

    cast_pack<<<20480, 256, 0, stream>>>(x, Wq, Wk, Wv, Wo, stdp, xb, Wqkv, Wob,
                                         out + 16777216L);
    qkv_gemm<<<dim3(128, 24), 256, 0, stream>>>(xb, Wqkv, bq, bk, bv, Qb, Kb, Vb);
    kv_reduce<<<dim3(64, 16), 256, 0, stream>>>(Kb, Vb, KVt, Ksum);
    attn_kernel<<<dim3(16, 64), 256, 0, stream>>>(Qb, KVt, Ksum, stdp, attn);
    out_gemm<<<dim3(128, 8), 256, 0, stream>>>(attn, Wob, bo, out);
}

// Round 3
// 381.485 us; speedup vs baseline: 1.1947x; 1.1947x over previous
//
#include <hip/hip_runtime.h>
#include <hip/hip_bf16.h>

#define DIMSZ 1024
#define SEQLEN 4096
#define NHEAD 16
#define NX 16777216L     // x elements
#define NW 1048576L      // weight elements each

typedef __attribute__((ext_vector_type(8))) short bf16x8;
typedef __attribute__((ext_vector_type(4))) float f32x4;

__device__ __forceinline__ unsigned short f2bf(float f) {
    union { float f; unsigned int i; } c; c.f = f;
    unsigned int x = c.i;
    unsigned int r = (x + 0x7fffu + ((x >> 16) & 1u)) >> 16;
    return (unsigned short)r;
}

// pack two f32 -> two bf16 (round-half-up) in one perm
__device__ __forceinline__ unsigned int pk2(float lo, float hi) {
    union { float f; unsigned int i; } a, b; a.f = lo; b.f = hi;
    return __builtin_amdgcn_perm(b.i + 0x8000u, a.i + 0x8000u, 0x07060302u);
}

__device__ __forceinline__ void unp4(const unsigned short* p, float* f) {
    uint2 w = *(const uint2*)p;
    union { unsigned int i; float f; } c;
    c.i = w.x << 16;           f[0] = c.f;
    c.i = w.x & 0xffff0000u;   f[1] = c.f;
    c.i = w.y << 16;           f[2] = c.f;
    c.i = w.y & 0xffff0000u;   f[3] = c.f;
}

__device__ __forceinline__ void unp8(const unsigned short* p, float* f) {
    uint4 w = *(const uint4*)p;
    union { unsigned int i; float f; } c;
    c.i = w.x << 16;           f[0] = c.f;
    c.i = w.x & 0xffff0000u;   f[1] = c.f;
    c.i = w.y << 16;           f[2] = c.f;
    c.i = w.y & 0xffff0000u;   f[3] = c.f;
    c.i = w.z << 16;           f[4] = c.f;
    c.i = w.z & 0xffff0000u;   f[5] = c.f;
    c.i = w.w << 16;           f[6] = c.f;
    c.i = w.w & 0xffff0000u;   f[7] = c.f;
}

__device__ __forceinline__ void async16(const void* g, void* l) {
    __builtin_amdgcn_global_load_lds(
        (const __attribute__((address_space(1))) void*)g,
        (__attribute__((address_space(3))) void*)l,
        16, 0, 0);
}

// ---------------- kernel 1: casts + weight packing + stdp passthrough ------
__global__ __launch_bounds__(256) void cast_pack(
    const float* __restrict__ x, const float* __restrict__ Wq,
    const float* __restrict__ Wk, const float* __restrict__ Wv,
    const float* __restrict__ Wo, const float* __restrict__ stdp,
    unsigned short* __restrict__ xb, unsigned short* __restrict__ Wqkv,
    unsigned short* __restrict__ Wob, float* __restrict__ outTail)
{
    long i4 = ((long)blockIdx.x * 256 + threadIdx.x) * 4;
    const float* src; unsigned short* dst; long off;
    if (i4 < NX)               { src = x;  dst = xb;          off = i4; }
    else if (i4 < NX + NW)     { src = Wq; dst = Wqkv;        off = i4 - NX; }
    else if (i4 < NX + 2*NW)   { src = Wk; dst = Wqkv + NW;   off = i4 - NX - NW; }
    else if (i4 < NX + 3*NW)   { src = Wv; dst = Wqkv + 2*NW; off = i4 - NX - 2*NW; }
    else                       { src = Wo; dst = Wob;         off = i4 - NX - 3*NW; }
    float4 v = *(const float4*)(src + off);
    union { unsigned short u[4]; uint2 p; } o;
    o.u[0] = f2bf(v.x); o.u[1] = f2bf(v.y); o.u[2] = f2bf(v.z); o.u[3] = f2bf(v.w);
    *(uint2*)(dst + off) = o.p;
    if (blockIdx.x == 0 && threadIdx.x < NHEAD) outTail[threadIdx.x] = stdp[threadIdx.x];
}

// ---------------- kernel 2: fused QKV GEMM --------------------------------
// swapped-operand mfma: acc[i][j][r] = C[row = m0+rw+16i+lr][col = c0+cw+16j+q4+r]
// epilogue: +bias, elu+1 (Q,K), pack bf16, LDS transpose, coalesced stores
// output layout head-major: [b][h][n][dh]
__global__ __launch_bounds__(256) void qkv_gemm(
    const unsigned short* __restrict__ A, const unsigned short* __restrict__ W,
    const float* __restrict__ bq, const float* __restrict__ bk,
    const float* __restrict__ bv,
    unsigned short* __restrict__ Qb, unsigned short* __restrict__ Kb,
    unsigned short* __restrict__ Vb)
{
    __shared__ unsigned short SM[9216];       // As(4096) + Bs(4096) in loop; Cs(128*72) in epilogue
    unsigned short* As = SM;
    unsigned short* Bs = SM + 4096;
    const int K = DIMSZ;
    int t = threadIdx.x;
    int wave = t >> 6, lane = t & 63;
    int lr = lane & 15, lk = (lane >> 4) * 8;
    int m0 = blockIdx.x * 128;
    int c0 = blockIdx.y * 128;
    int rw = (wave >> 1) * 64, cw = (wave & 1) * 64;

    const unsigned short* Ap = A + (long)(m0 + (t >> 2)) * K + (t & 3) * 8;
    const unsigned short* Wp = W + (long)(c0 + (t >> 2)) * K + (t & 3) * 8;
    char* AsW = (char*)As + wave * 1024;
    char* BsW = (char*)Bs + wave * 1024;

    f32x4 acc[4][4];
    #pragma unroll
    for (int i = 0; i < 4; ++i)
        #pragma unroll
        for (int j = 0; j < 4; ++j) acc[i][j] = (f32x4){0.f, 0.f, 0.f, 0.f};

    for (int k0 = 0; k0 < K; k0 += 32) {
        async16(Ap + k0,          AsW);
        async16(Ap + 64 * K + k0, AsW + 4096);
        async16(Wp + k0,          BsW);
        async16(Wp + 64 * K + k0, BsW + 4096);
        __syncthreads();
        bf16x8 af[4], bfr[4];
        #pragma unroll
        for (int i = 0; i < 4; ++i)
            af[i] = *(const bf16x8*)(As + (rw + 16 * i + lr) * 32 + lk);
        #pragma unroll
        for (int j = 0; j < 4; ++j)
            bfr[j] = *(const bf16x8*)(Bs + (cw + 16 * j + lr) * 32 + lk);
        #pragma unroll
        for (int i = 0; i < 4; ++i)
            #pragma unroll
            for (int j = 0; j < 4; ++j)
                acc[i][j] = __builtin_amdgcn_mfma_f32_16x16x32_bf16(bfr[j], af[i], acc[i][j], 0, 0, 0);
        __syncthreads();
    }

    // epilogue: two passes (64 cols = exactly one head each)
    unsigned short* Cs = SM;     // 128 rows x stride 72 shorts
    int q4 = (lane >> 4) * 4;
    int b = m0 >> 12;
    #pragma unroll
    for (int p = 0; p < 2; ++p) {
        int hh = (c0 >> 6) + p;          // global head slot 0..47
        int proj = hh >> 4, h = hh & 15;
        if ((wave & 1) == p) {
            bool qk = proj < 2;
            const float* bias = proj == 0 ? bq : (proj == 1 ? bk : bv);
            int cb = (c0 & 1023) + p * 64;
            #pragma unroll
            for (int j = 0; j < 4; ++j) {
                int dh0 = 16 * j + q4;
                float b0 = bias[cb + dh0], b1 = bias[cb + dh0 + 1];
                float b2 = bias[cb + dh0 + 2], b3 = bias[cb + dh0 + 3];
                #pragma unroll
                for (int i = 0; i < 4; ++i) {
                    float v0 = acc[i][j][0] + b0, v1 = acc[i][j][1] + b1;
                    float v2 = acc[i][j][2] + b2, v3 = acc[i][j][3] + b3;
                    if (qk) {
                        v0 = v0 > 0.f ? v0 + 1.f : __expf(v0);
                        v1 = v1 > 0.f ? v1 + 1.f : __expf(v1);
                        v2 = v2 > 0.f ? v2 + 1.f : __expf(v2);
                        v3 = v3 > 0.f ? v3 + 1.f : __expf(v3);
                    }
                    int row = rw + 16 * i + lr;
                    uint2 pkd; pkd.x = pk2(v0, v1); pkd.y = pk2(v2, v3);
                    *(uint2*)(Cs + row * 72 + dh0) = pkd;
                }
            }
        }
        __syncthreads();
        unsigned short* dstp = proj == 0 ? Qb : (proj == 1 ? Kb : Vb);
        #pragma unroll
        for (int u = 0; u < 4; ++u) {
            int row = u * 32 + (t >> 3);
            int n = (m0 + row) & 4095;
            long a = (((long)(b * 16 + h)) * SEQLEN + n) * 64 + (t & 7) * 8;
            *(uint4*)(dstp + a) = *(const uint4*)(Cs + row * 72 + (t & 7) * 8);
        }
        __syncthreads();
    }
}

// ---------------- kernel 3: KV partials + Ksum partials (no atomics) -------
// KVp[split][bh][v][d] = sum over 256 rows of V[n][v]*K[n][d]
__global__ __launch_bounds__(256) void kv_reduce(
    const unsigned short* __restrict__ Kb, const unsigned short* __restrict__ Vb,
    float* __restrict__ KVp, float* __restrict__ Ksump)
{
    __shared__ float red[4096];
    __shared__ float redk[64];
    int bh = blockIdx.x, split = blockIdx.y;
    int t = threadIdx.x;
    int dblk = t & 7, vblk = (t >> 3) & 7, nsub = t >> 6;
    int d0 = dblk * 8, v0 = vblk * 8;
    long rbase = ((long)bh * SEQLEN + split * 256 + nsub * 64) * 64;
    const unsigned short* Kp = Kb + rbase + d0;
    const unsigned short* Vp = Vb + rbase + v0;

    float acc[8][8];
    #pragma unroll
    for (int a = 0; a < 8; ++a)
        #pragma unroll
        for (int c = 0; c < 8; ++c) acc[a][c] = 0.f;
    float ks[8] = {0.f, 0.f, 0.f, 0.f, 0.f, 0.f, 0.f, 0.f};

    for (int i = 0; i < 64; ++i) {
        float kf[8], vf[8];
        unp8(Kp + (long)i * 64, kf);
        unp8(Vp + (long)i * 64, vf);
        if (vblk == 0) {
            #pragma unroll
            for (int d = 0; d < 8; ++d) ks[d] += kf[d];
        }
        #pragma unroll
        for (int vi = 0; vi < 8; ++vi)
            #pragma unroll
            for (int di = 0; di < 8; ++di) acc[vi][di] += vf[vi] * kf[di];
    }

    // cross-wave (nsub) reduce through LDS
    for (int p = 0; p < 4; ++p) {
        if (nsub == p) {
            #pragma unroll
            for (int vi = 0; vi < 8; ++vi)
                #pragma unroll
                for (int di = 0; di < 8; ++di) {
                    float* a = &red[(v0 + vi) * 64 + d0 + di];
                    if (p == 0) *a = acc[vi][di]; else *a += acc[vi][di];
                }
            if (vblk == 0) {
                #pragma unroll
                for (int di = 0; di < 8; ++di) {
                    float* a = &redk[d0 + di];
                    if (p == 0) *a = ks[di]; else *a += ks[di];
                }
            }
        }
        __syncthreads();
    }

    float* kp = KVp + ((long)split * 64 + bh) * 4096;
    #pragma unroll
    for (int u = 0; u < 4; ++u) {
        int idx = (u * 256 + t) * 4;
        *(float4*)(kp + idx) = *(const float4*)(red + idx);
    }
    if (t < 16)
        *(float4*)(Ksump + ((long)split * 64 + bh) * 64 + t * 4) = *(const float4*)(redk + t * 4);
}

// ---------------- kernel 3b: fold partials -> KV bf16 + Ksum f32 ----------
__global__ __launch_bounds__(256) void kv_final(
    const float* __restrict__ KVp, const float* __restrict__ Ksump,
    unsigned short* __restrict__ KVb, float* __restrict__ Ksum)
{
    int bh = blockIdx.x, t = threadIdx.x;
    float s[16];
    #pragma unroll
    for (int g = 0; g < 16; ++g) s[g] = 0.f;
    for (int sp = 0; sp < 16; ++sp) {
        const float* src = KVp + ((long)sp * 64 + bh) * 4096 + t * 16;
        #pragma unroll
        for (int g = 0; g < 4; ++g) {
            float4 v = *(const float4*)(src + g * 4);
            s[g * 4 + 0] += v.x; s[g * 4 + 1] += v.y;
            s[g * 4 + 2] += v.z; s[g * 4 + 3] += v.w;
        }
    }
    uint4 o0, o1;
    o0.x = pk2(s[0], s[1]);  o0.y = pk2(s[2], s[3]);
    o0.z = pk2(s[4], s[5]);  o0.w = pk2(s[6], s[7]);
    o1.x = pk2(s[8], s[9]);  o1.y = pk2(s[10], s[11]);
    o1.z = pk2(s[12], s[13]); o1.w = pk2(s[14], s[15]);
    *(uint4*)(KVb + (long)bh * 4096 + t * 16) = o0;
    *(uint4*)(KVb + (long)bh * 4096 + t * 16 + 8) = o1;
    if (t < 16) {
        float4 a = {0.f, 0.f, 0.f, 0.f};
        // 16 splits total (bugfix: was 64)
        for (int p = 0; p < 16; p += 4) {
            #pragma unroll
            for (int q = 0; q < 4; ++q) {
                float4 v = *(const float4*)(Ksump + ((long)(p + q) * 64 + bh) * 64 + t * 4);
                a.x += v.x; a.y += v.y; a.z += v.z; a.w += v.w;
            }
        }
        *(float4*)(Ksum + bh * 64 + t * 4) = a;
    }
}

// ---------------- kernel 4: denom + numerator MFMA + scale -> attn bf16 ----
// attn output layout: [b][n][h][dh] (= row-major (b,n,1024))
__global__ __launch_bounds__(256) void attn_kernel(
    const unsigned short* __restrict__ Qb, const unsigned short* __restrict__ KVb,
    const float* __restrict__ Ksum, const float* __restrict__ stdp,
    unsigned short* __restrict__ attn)
{
    __shared__ unsigned short Bsh[64 * 72];   // KV bf16 [v][d], stride 72
    __shared__ unsigned short Cs[256 * 72];   // output staging
    __shared__ float ksum_s[64];
    __shared__ float dinv[256];
    int t = threadIdx.x;
    int rc = blockIdx.x;   // 16 row-chunks of 256
    int bh = blockIdx.y;   // 64
    int b = bh >> 4, h = bh & 15;

    {   // load KV (8 KB) into padded LDS — full 64 shorts per row (bugfix)
        int v = t >> 2, doff = (t & 3) * 16;
        const unsigned short* src = KVb + (long)bh * 4096 + v * 64 + doff;
        *(uint4*)(Bsh + v * 72 + doff)     = *(const uint4*)(src);
        *(uint4*)(Bsh + v * 72 + doff + 8) = *(const uint4*)(src + 8);
        if (t < 64) ksum_s[t] = Ksum[bh * 64 + t];
    }
    __syncthreads();

    // denominator for row n = rc*256 + t (contiguous 128B rows)
    int n = rc * 256 + t;
    const unsigned short* qrow = Qb + ((long)bh * SEQLEN + n) * 64;
    float s = 0.f;
    #pragma unroll
    for (int u = 0; u < 64; u += 4) {
        float qf[4]; unp4(qrow + u, qf);
        s += qf[0] * ksum_s[u] + qf[1] * ksum_s[u + 1] + qf[2] * ksum_s[u + 2] + qf[3] * ksum_s[u + 3];
    }
    float sg = 1.f / (1.f + __expf(-stdp[h]));
    dinv[t] = sg / (s + 1e-6f);

    // numerator: swapped-operand -> regs hold consecutive v
    int wave = t >> 6, lane = t & 63, lr = lane & 15, lk = (lane >> 4) * 8;
    int rowbase = rc * 256 + wave * 64;
    f32x4 acc[4][4];
    #pragma unroll
    for (int i = 0; i < 4; ++i)
        #pragma unroll
        for (int j = 0; j < 4; ++j) acc[i][j] = (f32x4){0.f, 0.f, 0.f, 0.f};

    #pragma unroll
    for (int s0 = 0; s0 < 64; s0 += 32) {
        bf16x8 af[4], bfr[4];
        #pragma unroll
        for (int i = 0; i < 4; ++i)
            af[i] = *(const bf16x8*)(Qb + ((long)bh * SEQLEN + rowbase + 16 * i + lr) * 64 + s0 + lk);
        #pragma unroll
        for (int j = 0; j < 4; ++j)
            bfr[j] = *(const bf16x8*)(Bsh + (16 * j + lr) * 72 + s0 + lk);
        #pragma unroll
        for (int i = 0; i < 4; ++i)
            #pragma unroll
            for (int j = 0; j < 4; ++j)
                acc[i][j] = __builtin_amdgcn_mfma_f32_16x16x32_bf16(bfr[j], af[i], acc[i][j], 0, 0, 0);
    }
    __syncthreads();   // dinv ready; Bsh no longer needed

    int q4 = (lane >> 4) * 4;
    #pragma unroll
    for (int j = 0; j < 4; ++j) {
        int v0c = 16 * j + q4;
        #pragma unroll
        for (int i = 0; i < 4; ++i) {
            int row = wave * 64 + 16 * i + lr;
            float d = dinv[row];
            uint2 pkd;
            pkd.x = pk2(acc[i][j][0] * d, acc[i][j][1] * d);
            pkd.y = pk2(acc[i][j][2] * d, acc[i][j][3] * d);
            *(uint2*)(Cs + row * 72 + v0c) = pkd;
        }
    }
    __syncthreads();
    #pragma unroll
    for (int u = 0; u < 8; ++u) {
        int row = u * 32 + (t >> 3);
        int nn = rc * 256 + row;
        long a = ((long)(b * SEQLEN + nn)) * DIMSZ + h * 64 + (t & 7) * 8;
        *(uint4*)(attn + a) = *(const uint4*)(Cs + row * 72 + (t & 7) * 8);
    }
}

// ---------------- kernel 5: output GEMM (attn @ Wo^T + bo), f32 out --------
// swapped-operand: regs hold 4 consecutive cols -> direct float4 stores
__global__ __launch_bounds__(256) void out_gemm(
    const unsigned short* __restrict__ A, const unsigned short* __restrict__ W,
    const float* __restrict__ bo, float* __restrict__ out)
{
    __shared__ unsigned short As[128 * 32];
    __shared__ unsigned short Bs[128 * 32];
    const int K = DIMSZ;
    int t = threadIdx.x;
    int wave = t >> 6, lane = t & 63;
    int lr = lane & 15, lk = (lane >> 4) * 8;
    int m0 = blockIdx.x * 128;
    int c0 = blockIdx.y * 128;
    int rw = (wave >> 1) * 64, cw = (wave & 1) * 64;

    const unsigned short* Ap = A + (long)(m0 + (t >> 2)) * K + (t & 3) * 8;
    const unsigned short* Wp = W + (long)(c0 + (t >> 2)) * K + (t & 3) * 8;
    char* AsW = (char*)As + wave * 1024;
    char* BsW = (char*)Bs + wave * 1024;

    f32x4 acc[4][4];
    #pragma unroll
    for (int i = 0; i < 4; ++i)
        #pragma unroll
        for (int j = 0; j < 4; ++j) acc[i][j] = (f32x4){0.f, 0.f, 0.f, 0.f};

    for (int k0 = 0; k0 < K; k0 += 32) {
        async16(Ap + k0,          AsW);
        async16(Ap + 64 * K + k0, AsW + 4096);
        async16(Wp + k0,          BsW);
        async16(Wp + 64 * K + k0, BsW + 4096);
        __syncthreads();
        bf16x8 af[4], bfr[4];
        #pragma unroll
        for (int i = 0; i < 4; ++i)
            af[i] = *(const bf16x8*)(As + (rw + 16 * i + lr) * 32 + lk);
        #pragma unroll
        for (int j = 0; j < 4; ++j)
            bfr[j] = *(const bf16x8*)(Bs + (cw + 16 * j + lr) * 32 + lk);
        #pragma unroll
        for (int i = 0; i < 4; ++i)
            #pragma unroll
            for (int j = 0; j < 4; ++j)
                acc[i][j] = __builtin_amdgcn_mfma_f32_16x16x32_bf16(bfr[j], af[i], acc[i][j], 0, 0, 0);
        __syncthreads();
    }

    int q4 = (lane >> 4) * 4;
    #pragma unroll
    for (int j = 0; j < 4; ++j) {
        int c = c0 + cw + 16 * j + q4;
        float4 b4 = *(const float4*)(bo + c);
        #pragma unroll
        for (int i = 0; i < 4; ++i) {
            int gm = m0 + rw + 16 * i + lr;
            float4 v;
            v.x = acc[i][j][0] + b4.x; v.y = acc[i][j][1] + b4.y;
            v.z = acc[i][j][2] + b4.z; v.w = acc[i][j][3] + b4.w;
            *(float4*)(out + (long)gm * DIMSZ + c) = v;
        }
    }
}

extern "C" void kernel_launch(void* const* d_in, const int* in_sizes, int n_in,
                              void* d_out, int out_size, void* d_ws, size_t ws_size,
                              hipStream_t stream) {
    const float* x    = (const float*)d_in[0];
    const float* Wq   = (const float*)d_in[1];
    const float* bq   = (const float*)d_in[2];
    const float* Wk   = (const float*)d_in[3];
    const float* bk   = (const float*)d_in[4];
    const float* Wv   = (const float*)d_in[5];
    const float* bv   = (const float*)d_in[6];
    const float* Wo   = (const float*)d_in[7];
    const float* bo   = (const float*)d_in[8];
    const float* stdp = (const float*)d_in[9];
    float* out = (float*)d_out;

    char* ws = (char*)d_ws;
    // region [0, 32MB): xb during cast+qkv; KVp after qkv; attn after kv_final
    unsigned short* xb   = (unsigned short*)(ws);
    float*          KVp  = (float*)(ws);                          // 16.8 MB
    unsigned short* attn = (unsigned short*)(ws);                 // 32 MB
    // region [32MB, 40MB): Wqkv during qkv; Ksump/KVb/Ksum after
    unsigned short* Wqkv = (unsigned short*)(ws + 33554432L);     // 6 MB
    float*          Ksump= (float*)(ws + 33554432L);              // 256 KB
    unsigned short* KVb  = (unsigned short*)(ws + 33816576L);     // 512 KB
    float*          Ksum = (float*)(ws + 34340864L);              // 16 KB
    unsigned short* Wob  = (unsigned short*)(ws + 39845888L);     // 2 MB
    unsigned short* Qb   = (unsigned short*)(ws + 41943040L);     // 32 MB
    unsigned short* Kb   = (unsigned short*)(ws + 75497472L);     // 32 MB
    unsigned short* Vb   = (unsigned short*)(ws + 109051904L);    // 32 MB

    cast_pack<<<20480, 256, 0, stream>>>(x, Wq, Wk, Wv, Wo, stdp, xb, Wqkv, Wob,
                                         out + 16777216L);
    qkv_gemm<<<dim3(128, 24), 256, 0, stream>>>(xb, Wqkv, bq, bk, bv, Qb, Kb, Vb);
    kv_reduce<<<dim3(64, 16), 256, 0, stream>>>(Kb, Vb, KVp, Ksump);
    kv_final<<<64, 256, 0, stream>>>(KVp, Ksump, KVb, Ksum);
    attn_kernel<<<dim3(16, 64), 256, 0, stream>>>(Qb, KVb, Ksum, stdp, attn);
    out_gemm<<<dim3(128, 8), 256, 0, stream>>>(attn, Wob, bo, out);
}